// Round 3
// baseline (230.493 us; speedup 1.0000x reference)
//
#include <hip/hip_runtime.h>
#include <math.h>

// Reverse cumulative max (suffix max) along last dim.
// x: (8,1,2048,2048) fp32 -> 16384 rows of W=2048. One wave per row.
//
// Round 3: ALL global accesses fully coalesced (lane i <-> float4 #(64k+i),
// 8 cache lines per instruction instead of 64). The per-lane-contiguous
// ownership required by the serial scan is produced by an XOR-swizzled LDS
// transpose (sigma(j) = j ^ ((j>>3)&7) — measured 0 bank conflicts in R2).
// Row processed as two 1024-float halves (right first, carry max leftward)
// => 4 KiB LDS per wave, no __syncthreads (private per-wave LDS slices,
// DS pipe is in-order per wave).

#define ROW_W 2048
#define HALF_F4 256          // float4 slots per half-row
#define WAVES_PER_BLOCK 4

__device__ __forceinline__ int swz(int j) { return j ^ ((j >> 3) & 7); }

__global__ __launch_bounds__(256) void suffix_max_kernel(
    const float* __restrict__ x, float* __restrict__ out, int nrows) {
  __shared__ float4 lds[WAVES_PER_BLOCK][HALF_F4];  // 4 KiB/wave, 16 KiB/block

  const int wave = threadIdx.x >> 6;
  const int lane = threadIdx.x & 63;
  const int row  = blockIdx.x * WAVES_PER_BLOCK + wave;
  if (row >= nrows) return;  // wave-uniform; no barriers anywhere

  const float4* rin  = (const float4*)(x   + (size_t)row * ROW_W);
  float4*       rout = (float4*)      (out + (size_t)row * ROW_W);

  // Coalesced load of the whole row, all 8 instructions issued up front.
  float4 c[8];
#pragma unroll
  for (int k = 0; k < 8; ++k) c[k] = rin[64 * k + lane];

  float carry = -INFINITY;  // suffix max of everything right of current half

#pragma unroll
  for (int h = 1; h >= 0; --h) {  // right half first, then left
    // Transpose in: write coalesced-ownership pattern (j = 64k + lane).
#pragma unroll
    for (int k = 0; k < 4; ++k) {
      int j = 64 * k + lane;
      lds[wave][swz(j)] = c[4 * h + k];
    }
    // Read per-lane-contiguous pattern (j = 4*lane + k): lane owns
    // floats [16*lane, 16*lane+16) of this half.
    float4 v[4];
#pragma unroll
    for (int k = 0; k < 4; ++k) {
      int j = 4 * lane + k;
      v[k] = lds[wave][swz(j)];
    }

    // Serial suffix max over the lane's 16 floats (right-to-left).
    float run = -INFINITY;
#pragma unroll
    for (int k = 3; k >= 0; --k) {
      v[k].w = fmaxf(v[k].w, run);
      v[k].z = fmaxf(v[k].z, v[k].w);
      v[k].y = fmaxf(v[k].y, v[k].z);
      v[k].x = fmaxf(v[k].x, v[k].y);
      run = v[k].x;
    }

    // Wave-wide inclusive suffix scan of per-lane maxes.
    float inc = run;
#pragma unroll
    for (int off = 1; off < 64; off <<= 1) {
      float o = __shfl_down(inc, off, 64);
      if (lane + off < 64) inc = fmaxf(inc, o);
    }
    float excl = __shfl_down(inc, 1, 64);
    if (lane == 63) excl = -INFINITY;
    excl = fmaxf(excl, carry);
    float halfmax = __shfl(inc, 0, 64);  // max of this entire half

#pragma unroll
    for (int k = 0; k < 4; ++k) {
      v[k].x = fmaxf(v[k].x, excl);
      v[k].y = fmaxf(v[k].y, excl);
      v[k].z = fmaxf(v[k].z, excl);
      v[k].w = fmaxf(v[k].w, excl);
    }

    // Transpose out: write per-lane pattern, read coalesced, store 1 KiB/instr.
#pragma unroll
    for (int k = 0; k < 4; ++k) {
      int j = 4 * lane + k;
      lds[wave][swz(j)] = v[k];
    }
#pragma unroll
    for (int k = 0; k < 4; ++k) {
      int j = 64 * k + lane;
      rout[h * HALF_F4 + 64 * k + lane] = lds[wave][swz(j)];
    }

    carry = fmaxf(carry, halfmax);
  }
}

extern "C" void kernel_launch(void* const* d_in, const int* in_sizes, int n_in,
                              void* d_out, int out_size, void* d_ws, size_t ws_size,
                              hipStream_t stream) {
  const float* x = (const float*)d_in[0];
  float* out = (float*)d_out;
  const int nrows = out_size / ROW_W;  // 16384
  const int blocks = (nrows + WAVES_PER_BLOCK - 1) / WAVES_PER_BLOCK;
  suffix_max_kernel<<<blocks, 256, 0, stream>>>(x, out, nrows);
}